// Round 7
// baseline (5417.425 us; speedup 1.0000x reference)
//
#include <hip/hip_runtime.h>
#include <math.h>

// Problem constants (from reference)
#define TEMP_INV 20.0f   // 1/TEMP
#define MM 8192
#define NN 2048
#define HH 1024
#define ETA_IT 10
#define SLD 72           // LDS row stride in bf16 elems (64 + 8 pad -> 144B rows; wave b128 frag reads land 8 dwords/bank on all 32 banks = even minimum)

typedef float4 f4;
typedef unsigned short u16;
using short8 = __attribute__((ext_vector_type(8))) short;   // 8 bf16 = 4 VGPRs (guide-verified MFMA frag type)
using f32x4  = __attribute__((ext_vector_type(4))) float;   // MFMA accumulator

// ---------------- bf16 helpers (RNE) ----------------
__device__ __forceinline__ u16 f2bf(float x) {
  union { float f; unsigned u; } v; v.f = x;
  unsigned r = v.u + 0x7FFFu + ((v.u >> 16) & 1u);
  return (u16)(r >> 16);
}
__device__ __forceinline__ float bf2f(u16 h) {
  union { unsigned u; float f; } v; v.u = ((unsigned)h) << 16;
  return v.f;
}

// ---------------- reduction helpers ----------------
__device__ __forceinline__ float waveReduceSum(float v) {
#pragma unroll
  for (int off = 32; off > 0; off >>= 1) v += __shfl_xor(v, off, 64);
  return v;
}
__device__ __forceinline__ float waveReduceMax(float v) {
#pragma unroll
  for (int off = 32; off > 0; off >>= 1) v = fmaxf(v, __shfl_xor(v, off, 64));
  return v;
}
__device__ __forceinline__ float blockReduceSum(float v, float* tmp) {
  int tid = threadIdx.x;
  v = waveReduceSum(v);
  if ((tid & 63) == 0) tmp[tid >> 6] = v;
  __syncthreads();
  float r = tmp[0] + tmp[1] + tmp[2] + tmp[3];
  __syncthreads();
  return r;
}
__device__ __forceinline__ float blockReduceMax(float v, float* tmp) {
  int tid = threadIdx.x;
  v = waveReduceMax(v);
  if ((tid & 63) == 0) tmp[tid >> 6] = v;
  __syncthreads();
  float r = fmaxf(fmaxf(tmp[0], tmp[1]), fmaxf(tmp[2], tmp[3]));
  __syncthreads();
  return r;
}

// ---------------- row normalize + bf16 split: dst = l2norm(src[row]), H=1024 ----------------
__global__ __launch_bounds__(256) void rownorm_split_k(const float* __restrict__ src,
                                                       float* __restrict__ dst,
                                                       u16* __restrict__ dhi,
                                                       u16* __restrict__ dlo) {
  __shared__ float tmp[4];
  int row = blockIdx.x;
  int tid = threadIdx.x;
  f4 v = *(const f4*)(src + (size_t)row * HH + tid * 4);
  float ss = v.x * v.x + v.y * v.y + v.z * v.z + v.w * v.w;
  ss = blockReduceSum(ss, tmp);
  float inv = 1.0f / fmaxf(sqrtf(ss), 1e-12f);
  v.x *= inv; v.y *= inv; v.z *= inv; v.w *= inv;
  *(f4*)(dst + (size_t)row * HH + tid * 4) = v;
  union { u16 u[4]; uint2 q; } H, L;
  float vv[4] = {v.x, v.y, v.z, v.w};
#pragma unroll
  for (int j = 0; j < 4; ++j) {
    H.u[j] = f2bf(vv[j]);
    L.u[j] = f2bf(vv[j] - bf2f(H.u[j]));
  }
  *(uint2*)(dhi + (size_t)row * HH + tid * 4) = H.q;
  *(uint2*)(dlo + (size_t)row * HH + tid * 4) = L.q;
}

// ---------------- iter-0 shortcut ----------------
// qcm[h] = colsum(qn)[h] * 0.5 / N^2   (c1=0.5-prescaled delta_B1 row; exact since B_init=0)
__global__ __launch_bounds__(256) void colmean_k(const float* __restrict__ qn,
                                                 float* __restrict__ qcm) {
  int h = blockIdx.x * 256 + threadIdx.x;
  float s = 0.f;
  for (int n = 0; n < NN; ++n) s += qn[(size_t)n * HH + h];
  qcm[h] = s * (0.5f / ((float)NN * (float)NN));
}
// Bm[m,:] = l2norm(qcm + sqrt(2)*Q0[m,:])  + bf16 split
__global__ __launch_bounds__(256) void init0_k(const float* __restrict__ qcm,
                                               const float* __restrict__ noise,
                                               float* __restrict__ Bm,
                                               u16* __restrict__ bhi, u16* __restrict__ blo) {
  __shared__ float tmp[4];
  int m = blockIdx.x;
  int tid = threadIdx.x;
  const float c2 = 1.41421356237309515f;
  f4 qv = *(const f4*)(qcm + tid * 4);
  f4 nv = *(const f4*)(noise + (size_t)m * HH + tid * 4);
  f4 v = make_float4(qv.x + c2 * nv.x, qv.y + c2 * nv.y, qv.z + c2 * nv.z, qv.w + c2 * nv.w);
  float ss = v.x * v.x + v.y * v.y + v.z * v.z + v.w * v.w;
  ss = blockReduceSum(ss, tmp);
  float inv = 1.0f / fmaxf(sqrtf(ss), 1e-12f);
  v.x *= inv; v.y *= inv; v.z *= inv; v.w *= inv;
  *(f4*)(Bm + (size_t)m * HH + tid * 4) = v;
  union { u16 u[4]; uint2 q; } H, L;
  float vv[4] = {v.x, v.y, v.z, v.w};
#pragma unroll
  for (int j = 0; j < 4; ++j) {
    H.u[j] = f2bf(vv[j]);
    L.u[j] = f2bf(vv[j] - bf2f(H.u[j]));
  }
  *(uint2*)(bhi + (size_t)m * HH + tid * 4) = H.q;
  *(uint2*)(blo + (size_t)m * HH + tid * 4) = L.q;
}

// ---------------- split transpose: src fp32 [R][C] -> hiT/loT bf16 [C][R] ----------------
__global__ __launch_bounds__(256) void transpose_split_k(const float* __restrict__ src,
                                                         u16* __restrict__ hiT,
                                                         u16* __restrict__ loT,
                                                         int R, int C) {
  __shared__ float T[32][33];
  int c0 = blockIdx.x * 32, r0 = blockIdx.y * 32;
  int t = threadIdx.x;
  int j = t & 31, i4 = t >> 5;  // j fastest for coalescing
#pragma unroll
  for (int ii = 0; ii < 4; ++ii) {
    int i = i4 * 4 + ii;
    T[i][j] = src[(size_t)(r0 + i) * C + c0 + j];
  }
  __syncthreads();
#pragma unroll
  for (int ii = 0; ii < 4; ++ii) {
    int i = i4 * 4 + ii;
    float v = T[j][i];  // transposed read, 33-stride -> conflict-free
    u16 h = f2bf(v);
    size_t o = (size_t)(c0 + i) * R + r0 + j;
    hiT[o] = h;
    loT[o] = f2bf(v - bf2f(h));
  }
}

// ---------------- cos_sim: out[n*(MM+1)] = (qn . k/||k||) / TEMP ----------------
__global__ __launch_bounds__(256) void cos_k(const float* __restrict__ qn,
                                             const float* __restrict__ k,
                                             float* __restrict__ out) {
  __shared__ float tmp[4];
  int row = blockIdx.x;
  int tid = threadIdx.x;
  f4 a = *(const f4*)(qn + (size_t)row * HH + tid * 4);
  f4 b = *(const f4*)(k + (size_t)row * HH + tid * 4);
  float dot = a.x * b.x + a.y * b.y + a.z * b.z + a.w * b.w;
  float kk = b.x * b.x + b.y * b.y + b.z * b.z + b.w * b.w;
  dot = blockReduceSum(dot, tmp);
  kk = blockReduceSum(kk, tmp);
  if (tid == 0)
    out[(size_t)row * (MM + 1)] = dot / fmaxf(sqrtf(kk), 1e-12f) * TEMP_INV;
}

// ---------------- softmax row stats over L [MM, NN] -> E = exp((L-mx)/T) as bf16 hi/lo ----------------
// sA[m] = 1/(sum_e * N)  (P/N = e*sA);  sB[m] = sum(e*L)/(sum_e*N) = mean(P*L)
__global__ __launch_bounds__(256) void rowstats_k(const float* __restrict__ L,
                                                  u16* __restrict__ Ehi, u16* __restrict__ Elo,
                                                  float* __restrict__ sA,
                                                  float* __restrict__ sB) {
  __shared__ float tmp[4];
  int m = blockIdx.x;
  int tid = threadIdx.x;
  const float* row = L + (size_t)m * NN;
  f4 v0 = *(const f4*)(row + tid * 8);
  f4 v1 = *(const f4*)(row + tid * 8 + 4);
  float vals[8] = {v0.x, v0.y, v0.z, v0.w, v1.x, v1.y, v1.z, v1.w};
  float mx = vals[0];
#pragma unroll
  for (int j = 1; j < 8; ++j) mx = fmaxf(mx, vals[j]);
  mx = blockReduceMax(mx, tmp);
  float e[8], es = 0.f, els = 0.f;
#pragma unroll
  for (int j = 0; j < 8; ++j) {
    e[j] = expf((vals[j] - mx) * TEMP_INV);
    es += e[j];
    els += e[j] * vals[j];
  }
  es = blockReduceSum(es, tmp);
  els = blockReduceSum(els, tmp);
  union { u16 u[8]; uint4 q; } H, Lo;
#pragma unroll
  for (int j = 0; j < 8; ++j) {
    H.u[j] = f2bf(e[j]);
    Lo.u[j] = f2bf(e[j] - bf2f(H.u[j]));
  }
  *(uint4*)(Ehi + (size_t)m * NN + tid * 8) = H.q;
  *(uint4*)(Elo + (size_t)m * NN + tid * 8) = Lo.q;
  if (tid == 0) {
    float inv = 1.0f / (es * (float)NN);
    sA[m] = inv;
    sB[m] = els * inv;
  }
}

// ---------------- split-bf16 MFMA GEMM core ----------------
// C[m][n] = sum_k A[m][k]*B[n][k]  (both operands T-form: [row][k], k contiguous)
// fp32 emulated via extended K' = 3K: [A_hi*B_hi | A_hi*B_lo | A_lo*B_hi]
// Block 128x128, 4 waves in 2x2, each wave 64x64 = 4x4 frags of 16x16, mfma_f32_16x16x32_bf16.
__device__ __forceinline__ void gemm_core(const u16* __restrict__ Ahi, const u16* __restrict__ Alo,
                                          int lda,
                                          const u16* __restrict__ Bhi, const u16* __restrict__ Blo,
                                          int ldb, int K, int m0, int n0, int tid,
                                          u16* As, u16* Bs, f32x4 acc[4][4]) {
  const int lane = tid & 63, w = tid >> 6;
  const int wr = w >> 1, wc = w & 1;
  const int fr = lane & 15, kg = lane >> 4;
  const int nt = 3 * K / 64;
  for (int kt = 0; kt < nt; ++kt) {
    const int reg = (kt * 64) / K;  // 0: hi*hi, 1: hi*lo, 2: lo*hi
    const int k0 = kt * 64 - reg * K;
    const u16* asrc = (reg < 2) ? Ahi : Alo;
    const u16* bsrc = (reg == 1) ? Blo : Bhi;
    // stage 128x64 A-tile and B-tile (16B granules, coalesced; LDS rows padded to 144B)
#pragma unroll
    for (int rep = 0; rep < 4; ++rep) {
      int slot = tid + rep * 256;
      int x = slot >> 3, c8 = (slot & 7) << 3;
      *(uint4*)(As + x * SLD + c8) = *(const uint4*)(asrc + (size_t)(m0 + x) * lda + k0 + c8);
      *(uint4*)(Bs + x * SLD + c8) = *(const uint4*)(bsrc + (size_t)(n0 + x) * ldb + k0 + c8);
    }
    __syncthreads();
#pragma unroll
    for (int ks = 0; ks < 64; ks += 32) {
      short8 a[4], b[4];
#pragma unroll
      for (int mi = 0; mi < 4; ++mi)
        a[mi] = *(const short8*)(As + (wr * 64 + mi * 16 + fr) * SLD + ks + kg * 8);
#pragma unroll
      for (int ni = 0; ni < 4; ++ni)
        b[ni] = *(const short8*)(Bs + (wc * 64 + ni * 16 + fr) * SLD + ks + kg * 8);
#pragma unroll
      for (int mi = 0; mi < 4; ++mi)
#pragma unroll
        for (int ni = 0; ni < 4; ++ni)
          acc[mi][ni] = __builtin_amdgcn_mfma_f32_16x16x32_bf16(a[mi], b[ni], acc[mi][ni], 0, 0, 0);
    }
    __syncthreads();
  }
}

#define GEMM_PROLOGUE()                                     \
  __shared__ u16 As[128 * SLD], Bs[128 * SLD];              \
  int tid = threadIdx.x;                                    \
  f32x4 acc[4][4];                                          \
  {                                                         \
    f32x4 z = {0.f, 0.f, 0.f, 0.f};                         \
    _Pragma("unroll") for (int i = 0; i < 4; ++i)           \
        _Pragma("unroll") for (int j = 0; j < 4; ++j) acc[i][j] = z; \
  }                                                         \
  const int lane = tid & 63, wv = tid >> 6;                 \
  const int wr = wv >> 1, wc = wv & 1;                      \
  const int fr = lane & 15, kg = lane >> 4;

// C/D frag map (m89/m91-verified): row = 4*(lane>>4)+reg, col = lane&15

// ---------------- L = B @ qn^T  [MM x NN], K=HH ----------------
__global__ __launch_bounds__(256) void gemm_L_k(const u16* __restrict__ Ahi, const u16* __restrict__ Alo,
                                                const u16* __restrict__ Bhi, const u16* __restrict__ Blo,
                                                float* __restrict__ L) {
  GEMM_PROLOGUE();
  int n0 = blockIdx.x * 128, m0 = blockIdx.y * 128;
  gemm_core(Ahi, Alo, HH, Bhi, Blo, HH, HH, m0, n0, tid, As, Bs, acc);
#pragma unroll
  for (int mi = 0; mi < 4; ++mi)
#pragma unroll
    for (int r = 0; r < 4; ++r) {
      int m = m0 + wr * 64 + mi * 16 + kg * 4 + r;
      float* dst = L + (size_t)m * NN + n0 + wc * 64 + fr;
#pragma unroll
      for (int ni = 0; ni < 4; ++ni) dst[ni * 16] = acc[mi][ni][r];
    }
}

// ---------------- dB1 = (E @ qn)*sA[m] - sB[m]*B  [MM x HH], K=NN ----------------
__global__ __launch_bounds__(256) void gemm_dB1_k(const u16* __restrict__ Ahi, const u16* __restrict__ Alo,
                                                  const u16* __restrict__ Bhi, const u16* __restrict__ Blo,
                                                  const float* __restrict__ Bm,
                                                  const float* __restrict__ sA,
                                                  const float* __restrict__ sB,
                                                  float* __restrict__ dB1) {
  GEMM_PROLOGUE();
  int n0 = blockIdx.x * 128, m0 = blockIdx.y * 128;
  gemm_core(Ahi, Alo, NN, Bhi, Blo, NN, NN, m0, n0, tid, As, Bs, acc);
#pragma unroll
  for (int mi = 0; mi < 4; ++mi)
#pragma unroll
    for (int r = 0; r < 4; ++r) {
      int m = m0 + wr * 64 + mi * 16 + kg * 4 + r;
      float a = sA[m], bc = sB[m];
      size_t base = (size_t)m * HH + n0 + wc * 64 + fr;
#pragma unroll
      for (int ni = 0; ni < 4; ++ni)
        dB1[base + ni * 16] = acc[mi][ni][r] * a - bc * Bm[base + ni * 16];
    }
}

// ---------------- Gp[slice] = B[slice]^T @ dB1[slice]  [HH x HH], split-K over MM ----------------
__global__ __launch_bounds__(256) void gemm_G_k(const u16* __restrict__ Ahi, const u16* __restrict__ Alo,
                                                const u16* __restrict__ Bhi, const u16* __restrict__ Blo,
                                                float* __restrict__ Gp) {
  GEMM_PROLOGUE();
  int n0 = blockIdx.x * 128, m0 = blockIdx.y * 128;
  int kbase = blockIdx.z * (MM / 8);
  gemm_core(Ahi + kbase, Alo + kbase, MM, Bhi + kbase, Blo + kbase, MM, MM / 8, m0, n0, tid, As, Bs, acc);
  float* dst0 = Gp + (size_t)blockIdx.z * HH * HH;
#pragma unroll
  for (int mi = 0; mi < 4; ++mi)
#pragma unroll
    for (int r = 0; r < 4; ++r) {
      int h1 = m0 + wr * 64 + mi * 16 + kg * 4 + r;
      float* dst = dst0 + (size_t)h1 * HH + n0 + wc * 64 + fr;
#pragma unroll
      for (int ni = 0; ni < 4; ++ni) dst[ni * 16] = acc[mi][ni][r];
    }
}

// ---------------- G = (sum_s Gp[s]) / M ----------------
__global__ __launch_bounds__(256) void reduceG_k(const float* __restrict__ Gp,
                                                 float* __restrict__ G) {
  size_t i = ((size_t)blockIdx.x * 256 + threadIdx.x) * 4;
  f4 s = make_float4(0.f, 0.f, 0.f, 0.f);
#pragma unroll
  for (int sl = 0; sl < 8; ++sl) {
    f4 v = *(const f4*)(Gp + (size_t)sl * HH * HH + i);
    s.x += v.x; s.y += v.y; s.z += v.z; s.w += v.w;
  }
  const float invM = 1.0f / (float)MM;
  s.x *= invM; s.y *= invM; s.z *= invM; s.w *= invM;
  *(f4*)(G + i) = s;
}

// ---------------- upd = (1+c1)*B + c1*(B@G) + c1*dB1 + c2*noise  [MM x HH], K=HH ----------------
// (B operand = GT so that k=h' is contiguous; writes result in-place into dB1 buffer)
__global__ __launch_bounds__(256) void gemm_upd_k(const u16* __restrict__ Ahi, const u16* __restrict__ Alo,
                                                  const u16* __restrict__ Bhi, const u16* __restrict__ Blo,
                                                  const float* __restrict__ Bm,
                                                  const float* __restrict__ noise,
                                                  float* __restrict__ dB1, float c1, float c2) {
  GEMM_PROLOGUE();
  int n0 = blockIdx.x * 128, m0 = blockIdx.y * 128;
  gemm_core(Ahi, Alo, HH, Bhi, Blo, HH, HH, m0, n0, tid, As, Bs, acc);
  const float c1p = 1.0f + c1;
#pragma unroll
  for (int mi = 0; mi < 4; ++mi)
#pragma unroll
    for (int r = 0; r < 4; ++r) {
      int m = m0 + wr * 64 + mi * 16 + kg * 4 + r;
      size_t base = (size_t)m * HH + n0 + wc * 64 + fr;
#pragma unroll
      for (int ni = 0; ni < 4; ++ni) {
        size_t o = base + ni * 16;
        dB1[o] = c1 * acc[mi][ni][r] + c1p * Bm[o] + c1 * dB1[o] + c2 * noise[o];
      }
    }
}

// ---------------- out[n][1+m] = (qn @ B^T)/TEMP  [NN x MM], K=HH; row stride MM+1 ----------------
__global__ __launch_bounds__(256) void gemm_out_k(const u16* __restrict__ Ahi, const u16* __restrict__ Alo,
                                                  const u16* __restrict__ Bhi, const u16* __restrict__ Blo,
                                                  float* __restrict__ out) {
  GEMM_PROLOGUE();
  int n0 = blockIdx.x * 128, m0 = blockIdx.y * 128;  // n0: m-cols, m0: n-rows
  gemm_core(Ahi, Alo, HH, Bhi, Blo, HH, HH, m0, n0, tid, As, Bs, acc);
#pragma unroll
  for (int mi = 0; mi < 4; ++mi)
#pragma unroll
    for (int r = 0; r < 4; ++r) {
      int n = m0 + wr * 64 + mi * 16 + kg * 4 + r;
      float* dst = out + (size_t)n * (MM + 1) + 1 + n0 + wc * 64 + fr;
#pragma unroll
      for (int ni = 0; ni < 4; ++ni) dst[ni * 16] = acc[mi][ni][r] * TEMP_INV;
    }
}

extern "C" void kernel_launch(void* const* d_in, const int* in_sizes, int n_in, void* d_out,
                              int out_size, void* d_ws, size_t ws_size, hipStream_t stream) {
  (void)in_sizes; (void)n_in; (void)out_size; (void)ws_size;
  const float* q = (const float*)d_in[0];
  const float* k = (const float*)d_in[1];
  const float* noise = (const float*)d_in[3];
  float* out = (float*)d_out;

  // ---- workspace carve (bytes, 256B-aligned) ----
  char* w = (char*)d_ws;
  size_t off = 0;
  auto alloc = [&](size_t bytes) -> void* {
    void* p = w + off;
    off = (off + bytes + 255) & ~(size_t)255;
    return p;
  };
  float* qn     = (float*)alloc((size_t)NN * HH * 4);
  u16*   qn_hi  = (u16*)  alloc((size_t)NN * HH * 2);
  u16*   qn_lo  = (u16*)  alloc((size_t)NN * HH * 2);
  u16*   qnT_hi = (u16*)  alloc((size_t)HH * NN * 2);
  u16*   qnT_lo = (u16*)  alloc((size_t)HH * NN * 2);
  float* Bm     = (float*)alloc((size_t)MM * HH * 4);
  u16*   Bm_hi  = (u16*)  alloc((size_t)MM * HH * 2);
  u16*   Bm_lo  = (u16*)  alloc((size_t)MM * HH * 2);
  u16*   BmT_hi = (u16*)  alloc((size_t)HH * MM * 2);
  u16*   BmT_lo = (u16*)  alloc((size_t)HH * MM * 2);
  float* dB1    = (float*)alloc((size_t)MM * HH * 4);
  // E region (dead after gemm_dB1 each iter) overlays Gp and dB1T:
  u16*   E_hi   = (u16*)  alloc((size_t)MM * NN * 2);  // 33.5MB; also Gp (fp32, 8*HH*HH*4 = 32MB)
  u16*   E_lo   = (u16*)  alloc((size_t)MM * NN * 2);  // 33.5MB; also dB1T hi+lo (2 x 16.8MB)
  float* Gp     = (float*)E_hi;
  u16*   dB1T_hi = (u16*)E_lo;
  u16*   dB1T_lo = dB1T_hi + (size_t)HH * MM;
  float* G      = (float*)alloc((size_t)HH * HH * 4);
  u16*   GT_hi  = (u16*)  alloc((size_t)HH * HH * 2);
  u16*   GT_lo  = (u16*)  alloc((size_t)HH * HH * 2);
  float* sA     = (float*)alloc(MM * 4);
  float* sB     = (float*)alloc(MM * 4);
  float* qcm    = (float*)alloc(HH * 4);
  float* L = out;  // [MM][NN] logits scratch inside d_out; fully overwritten at the end

  // ---- setup ----
  rownorm_split_k<<<NN, 256, 0, stream>>>(q, qn, qn_hi, qn_lo);
  transpose_split_k<<<dim3(HH / 32, NN / 32), 256, 0, stream>>>(qn, qnT_hi, qnT_lo, NN, HH);
  colmean_k<<<HH / 256, 256, 0, stream>>>(qn, qcm);
  // iteration 0 exact shortcut (B_init = 0 -> uniform softmax, delta_B = 0)
  init0_k<<<MM, 256, 0, stream>>>(qcm, noise, Bm, Bm_hi, Bm_lo);
  transpose_split_k<<<dim3(HH / 32, MM / 32), 256, 0, stream>>>(Bm, BmT_hi, BmT_lo, MM, HH);

  for (int it = 1; it < ETA_IT; ++it) {
    float t = (float)it + 1.0f;
    float c1 = 0.5f / t;
    float c2 = sqrtf(2.0f / t);
    gemm_L_k<<<dim3(NN / 128, MM / 128), 256, 0, stream>>>(Bm_hi, Bm_lo, qn_hi, qn_lo, L);
    rowstats_k<<<MM, 256, 0, stream>>>(L, E_hi, E_lo, sA, sB);
    gemm_dB1_k<<<dim3(HH / 128, MM / 128), 256, 0, stream>>>(E_hi, E_lo, qnT_hi, qnT_lo, Bm, sA, sB, dB1);
    transpose_split_k<<<dim3(HH / 32, MM / 32), 256, 0, stream>>>(dB1, dB1T_hi, dB1T_lo, MM, HH);
    gemm_G_k<<<dim3(HH / 128, HH / 128, 8), 256, 0, stream>>>(BmT_hi, BmT_lo, dB1T_hi, dB1T_lo, Gp);
    reduceG_k<<<(HH * HH / 4) / 256, 256, 0, stream>>>(Gp, G);
    transpose_split_k<<<dim3(HH / 32, HH / 32), 256, 0, stream>>>(G, GT_hi, GT_lo, HH, HH);
    gemm_upd_k<<<dim3(HH / 128, MM / 128), 256, 0, stream>>>(
        Bm_hi, Bm_lo, GT_hi, GT_lo, Bm, noise + (size_t)it * MM * HH, dB1, c1, c2);
    rownorm_split_k<<<MM, 256, 0, stream>>>(dB1, Bm, Bm_hi, Bm_lo);
    transpose_split_k<<<dim3(HH / 32, MM / 32), 256, 0, stream>>>(Bm, BmT_hi, BmT_lo, MM, HH);
  }

  // ---- final output ----
  cos_k<<<NN, 256, 0, stream>>>(qn, k, out);
  gemm_out_k<<<dim3(MM / 128, NN / 128), 256, 0, stream>>>(qn_hi, qn_lo, Bm_hi, Bm_lo, out);
}

// Round 8
// 5176.678 us; speedup vs baseline: 1.0465x; 1.0465x over previous
//
#include <hip/hip_runtime.h>
#include <math.h>

// Problem constants (from reference)
#define TEMP_INV 20.0f   // 1/TEMP
#define MM 8192
#define NN 2048
#define HH 1024
#define ETA_IT 10

typedef float4 f4;
typedef unsigned short u16;
using short8 = __attribute__((ext_vector_type(8))) short;   // 8 bf16 = 4 VGPRs (MFMA frag)
using f32x4  = __attribute__((ext_vector_type(4))) float;   // MFMA accumulator

// ---------------- bf16 helpers (RNE) ----------------
__device__ __forceinline__ u16 f2bf(float x) {
  union { float f; unsigned u; } v; v.f = x;
  unsigned r = v.u + 0x7FFFu + ((v.u >> 16) & 1u);
  return (u16)(r >> 16);
}
__device__ __forceinline__ float bf2f(u16 h) {
  union { unsigned u; float f; } v; v.u = ((unsigned)h) << 16;
  return v.f;
}

// async global->LDS, 16B per lane; LDS dest is wave-uniform base + lane*16 (m104)
__device__ __forceinline__ void gload16(const u16* __restrict__ g, u16* l) {
  __builtin_amdgcn_global_load_lds((const __attribute__((address_space(1))) void*)g,
                                   (__attribute__((address_space(3))) void*)l, 16, 0, 0);
}

// bijective XCD-aware swizzle of (blockIdx.x, blockIdx.y); requires nwg % 8 == 0 (all our grids)
__device__ __forceinline__ void xcd_swz(int& bx, int& by) {
  int gx = gridDim.x;
  int nwg = gx * gridDim.y;
  int wg = blockIdx.y * gx + blockIdx.x;
  int cpx = nwg >> 3;
  int s = (wg & 7) * cpx + (wg >> 3);
  bx = s % gx;
  by = s / gx;
}

// ---------------- reduction helpers ----------------
__device__ __forceinline__ float waveReduceSum(float v) {
#pragma unroll
  for (int off = 32; off > 0; off >>= 1) v += __shfl_xor(v, off, 64);
  return v;
}
__device__ __forceinline__ float waveReduceMax(float v) {
#pragma unroll
  for (int off = 32; off > 0; off >>= 1) v = fmaxf(v, __shfl_xor(v, off, 64));
  return v;
}
__device__ __forceinline__ float blockReduceSum(float v, float* tmp) {
  int tid = threadIdx.x;
  v = waveReduceSum(v);
  if ((tid & 63) == 0) tmp[tid >> 6] = v;
  __syncthreads();
  float r = tmp[0] + tmp[1] + tmp[2] + tmp[3];
  __syncthreads();
  return r;
}
__device__ __forceinline__ float blockReduceMax(float v, float* tmp) {
  int tid = threadIdx.x;
  v = waveReduceMax(v);
  if ((tid & 63) == 0) tmp[tid >> 6] = v;
  __syncthreads();
  float r = fmaxf(fmaxf(tmp[0], tmp[1]), fmaxf(tmp[2], tmp[3]));
  __syncthreads();
  return r;
}

// ---------------- row normalize + bf16 split: dst = l2norm(src[row]), H=1024 ----------------
__global__ __launch_bounds__(256) void rownorm_split_k(const float* __restrict__ src,
                                                       float* __restrict__ dst,
                                                       u16* __restrict__ dhi,
                                                       u16* __restrict__ dlo) {
  __shared__ float tmp[4];
  int row = blockIdx.x;
  int tid = threadIdx.x;
  f4 v = *(const f4*)(src + (size_t)row * HH + tid * 4);
  float ss = v.x * v.x + v.y * v.y + v.z * v.z + v.w * v.w;
  ss = blockReduceSum(ss, tmp);
  float inv = 1.0f / fmaxf(sqrtf(ss), 1e-12f);
  v.x *= inv; v.y *= inv; v.z *= inv; v.w *= inv;
  *(f4*)(dst + (size_t)row * HH + tid * 4) = v;
  union { u16 u[4]; uint2 q; } H, L;
  float vv[4] = {v.x, v.y, v.z, v.w};
#pragma unroll
  for (int j = 0; j < 4; ++j) {
    H.u[j] = f2bf(vv[j]);
    L.u[j] = f2bf(vv[j] - bf2f(H.u[j]));
  }
  *(uint2*)(dhi + (size_t)row * HH + tid * 4) = H.q;
  *(uint2*)(dlo + (size_t)row * HH + tid * 4) = L.q;
}

// ---------------- iter-0 shortcut ----------------
// qcm[h] = colsum(qn)[h] * 0.5 / N^2   (c1=0.5-prescaled delta_B1 row; exact since B_init=0)
__global__ __launch_bounds__(256) void colmean_k(const float* __restrict__ qn,
                                                 float* __restrict__ qcm) {
  int h = blockIdx.x * 256 + threadIdx.x;
  float s = 0.f;
  for (int n = 0; n < NN; ++n) s += qn[(size_t)n * HH + h];
  qcm[h] = s * (0.5f / ((float)NN * (float)NN));
}
// Bm[m,:] = l2norm(qcm + sqrt(2)*Q0[m,:])  + bf16 split
__global__ __launch_bounds__(256) void init0_k(const float* __restrict__ qcm,
                                               const float* __restrict__ noise,
                                               float* __restrict__ Bm,
                                               u16* __restrict__ bhi, u16* __restrict__ blo) {
  __shared__ float tmp[4];
  int m = blockIdx.x;
  int tid = threadIdx.x;
  const float c2 = 1.41421356237309515f;
  f4 qv = *(const f4*)(qcm + tid * 4);
  f4 nv = *(const f4*)(noise + (size_t)m * HH + tid * 4);
  f4 v = make_float4(qv.x + c2 * nv.x, qv.y + c2 * nv.y, qv.z + c2 * nv.z, qv.w + c2 * nv.w);
  float ss = v.x * v.x + v.y * v.y + v.z * v.z + v.w * v.w;
  ss = blockReduceSum(ss, tmp);
  float inv = 1.0f / fmaxf(sqrtf(ss), 1e-12f);
  v.x *= inv; v.y *= inv; v.z *= inv; v.w *= inv;
  *(f4*)(Bm + (size_t)m * HH + tid * 4) = v;
  union { u16 u[4]; uint2 q; } H, L;
  float vv[4] = {v.x, v.y, v.z, v.w};
#pragma unroll
  for (int j = 0; j < 4; ++j) {
    H.u[j] = f2bf(vv[j]);
    L.u[j] = f2bf(vv[j] - bf2f(H.u[j]));
  }
  *(uint2*)(bhi + (size_t)m * HH + tid * 4) = H.q;
  *(uint2*)(blo + (size_t)m * HH + tid * 4) = L.q;
}

// ---------------- split transpose: src fp32 [R][C] -> hiT/loT bf16 [C][R] ----------------
__global__ __launch_bounds__(256) void transpose_split_k(const float* __restrict__ src,
                                                         u16* __restrict__ hiT,
                                                         u16* __restrict__ loT,
                                                         int R, int C) {
  __shared__ float T[32][33];
  int c0 = blockIdx.x * 32, r0 = blockIdx.y * 32;
  int t = threadIdx.x;
  int j = t & 31, i4 = t >> 5;  // j fastest for coalescing
#pragma unroll
  for (int ii = 0; ii < 4; ++ii) {
    int i = i4 * 4 + ii;
    T[i][j] = src[(size_t)(r0 + i) * C + c0 + j];
  }
  __syncthreads();
#pragma unroll
  for (int ii = 0; ii < 4; ++ii) {
    int i = i4 * 4 + ii;
    float v = T[j][i];  // transposed read, 33-stride -> conflict-free
    u16 h = f2bf(v);
    size_t o = (size_t)(c0 + i) * R + r0 + j;
    hiT[o] = h;
    loT[o] = f2bf(v - bf2f(h));
  }
}

// ---------------- cos_sim: out[n*(MM+1)] = (qn . k/||k||) / TEMP ----------------
__global__ __launch_bounds__(256) void cos_k(const float* __restrict__ qn,
                                             const float* __restrict__ k,
                                             float* __restrict__ out) {
  __shared__ float tmp[4];
  int row = blockIdx.x;
  int tid = threadIdx.x;
  f4 a = *(const f4*)(qn + (size_t)row * HH + tid * 4);
  f4 b = *(const f4*)(k + (size_t)row * HH + tid * 4);
  float dot = a.x * b.x + a.y * b.y + a.z * b.z + a.w * b.w;
  float kk = b.x * b.x + b.y * b.y + b.z * b.z + b.w * b.w;
  dot = blockReduceSum(dot, tmp);
  kk = blockReduceSum(kk, tmp);
  if (tid == 0)
    out[(size_t)row * (MM + 1)] = dot / fmaxf(sqrtf(kk), 1e-12f) * TEMP_INV;
}

// ---------------- softmax row stats over L [MM, NN] -> E = exp((L-mx)/T) as bf16 hi/lo ----------------
// sA[m] = 1/(sum_e * N)  (P/N = e*sA);  sB[m] = sum(e*L)/(sum_e*N) = mean(P*L)
__global__ __launch_bounds__(256) void rowstats_k(const float* __restrict__ L,
                                                  u16* __restrict__ Ehi, u16* __restrict__ Elo,
                                                  float* __restrict__ sA,
                                                  float* __restrict__ sB) {
  __shared__ float tmp[4];
  int m = blockIdx.x;
  int tid = threadIdx.x;
  const float* row = L + (size_t)m * NN;
  f4 v0 = *(const f4*)(row + tid * 8);
  f4 v1 = *(const f4*)(row + tid * 8 + 4);
  float vals[8] = {v0.x, v0.y, v0.z, v0.w, v1.x, v1.y, v1.z, v1.w};
  float mx = vals[0];
#pragma unroll
  for (int j = 1; j < 8; ++j) mx = fmaxf(mx, vals[j]);
  mx = blockReduceMax(mx, tmp);
  float e[8], es = 0.f, els = 0.f;
#pragma unroll
  for (int j = 0; j < 8; ++j) {
    e[j] = expf((vals[j] - mx) * TEMP_INV);
    es += e[j];
    els += e[j] * vals[j];
  }
  es = blockReduceSum(es, tmp);
  els = blockReduceSum(els, tmp);
  union { u16 u[8]; uint4 q; } H, Lo;
#pragma unroll
  for (int j = 0; j < 8; ++j) {
    H.u[j] = f2bf(e[j]);
    Lo.u[j] = f2bf(e[j] - bf2f(H.u[j]));
  }
  *(uint4*)(Ehi + (size_t)m * NN + tid * 8) = H.q;
  *(uint4*)(Elo + (size_t)m * NN + tid * 8) = Lo.q;
  if (tid == 0) {
    float inv = 1.0f / (es * (float)NN);
    sA[m] = inv;
    sB[m] = els * inv;
  }
}

// ---------------- split-bf16 MFMA GEMM core ----------------
// C[m][n] = sum_k A[m][k]*B[n][k]  (both operands T-form: [row][k], k contiguous)
// fp32 emulated via extended K' = 3K: [A_hi*B_hi | A_hi*B_lo | A_lo*B_hi]
// Block 128x128, 4 waves 2x2, wave=64x64 = 4x4 frags of 16x16, mfma_f32_16x16x32_bf16.
// Staging: global_load_lds width=16 into LINEAR LDS [128][64] with both-sides XOR
// swizzle (rule #21): source block pre-XORed by (row&7), ds_read applies same XOR ->
// frag reads land 8 dwords/bank on all 32 banks (even minimum), staging is DMA.
__device__ __forceinline__ void gemm_core(const u16* __restrict__ Ahi, const u16* __restrict__ Alo,
                                          int lda,
                                          const u16* __restrict__ Bhi, const u16* __restrict__ Blo,
                                          int ldb, int K, int m0, int n0, int tid,
                                          u16* As, u16* Bs, f32x4 acc[4][4]) {
  const int lane = tid & 63, wv = tid >> 6;
  const int wr = wv >> 1, wc = wv & 1;
  const int fr = lane & 15, kg = lane >> 4;
  const int lrow = lane >> 3;                    // 0..7: row within 8-row staging chunk
  const int sblk = ((lane & 7) ^ lrow) << 3;     // inverse-swizzled source block (elems)
  const int xoff = (kg ^ (fr & 7)) << 3;         // read-side swizzle (elems)
  const int nt = 3 * K / 64;
  for (int kt = 0; kt < nt; ++kt) {
    const int reg = (kt * 64) / K;  // 0: hi*hi, 1: hi*lo, 2: lo*hi
    const int k0 = kt * 64 - reg * K;
    const u16* asrc = (reg < 2) ? Ahi : Alo;
    const u16* bsrc = (reg == 1) ? Blo : Bhi;
    // stage 128x64 A and B tiles: 16 chunks of 8 rows each, 1KB per wave-issue
#pragma unroll
    for (int c4 = 0; c4 < 4; ++c4) {
      const int c = wv * 4 + c4;
      gload16(asrc + (size_t)(m0 + c * 8 + lrow) * lda + k0 + sblk, As + c * 512);
      gload16(bsrc + (size_t)(n0 + c * 8 + lrow) * ldb + k0 + sblk, Bs + c * 512);
    }
    __syncthreads();  // compiler drains vmcnt(0) here (m97 semantics)
#pragma unroll
    for (int ks = 0; ks < 64; ks += 32) {
      short8 a[4], b[4];
#pragma unroll
      for (int mi = 0; mi < 4; ++mi)
        a[mi] = *(const short8*)(As + (wr * 64 + mi * 16 + fr) * 64 + (ks ^ xoff));
#pragma unroll
      for (int ni = 0; ni < 4; ++ni)
        b[ni] = *(const short8*)(Bs + (wc * 64 + ni * 16 + fr) * 64 + (ks ^ xoff));
#pragma unroll
      for (int mi = 0; mi < 4; ++mi)
#pragma unroll
        for (int ni = 0; ni < 4; ++ni)
          acc[mi][ni] = __builtin_amdgcn_mfma_f32_16x16x32_bf16(a[mi], b[ni], acc[mi][ni], 0, 0, 0);
    }
    __syncthreads();
  }
}

#define GEMM_PROLOGUE()                                     \
  __shared__ u16 As[128 * 64], Bs[128 * 64];                \
  int tid = threadIdx.x;                                    \
  f32x4 acc[4][4];                                          \
  {                                                         \
    f32x4 z = {0.f, 0.f, 0.f, 0.f};                         \
    _Pragma("unroll") for (int i = 0; i < 4; ++i)           \
        _Pragma("unroll") for (int j = 0; j < 4; ++j) acc[i][j] = z; \
  }                                                         \
  const int lane = tid & 63, wv = tid >> 6;                 \
  const int wr = wv >> 1, wc = wv & 1;                      \
  const int fr = lane & 15, kg = lane >> 4;

// C/D frag map (m89/m91-verified): row = 4*(lane>>4)+reg, col = lane&15

// ---------------- L = B @ qn^T  [MM x NN], K=HH ----------------
__global__ __launch_bounds__(256) void gemm_L_k(const u16* __restrict__ Ahi, const u16* __restrict__ Alo,
                                                const u16* __restrict__ Bhi, const u16* __restrict__ Blo,
                                                float* __restrict__ L) {
  GEMM_PROLOGUE();
  int bx, by; xcd_swz(bx, by);
  int n0 = bx * 128, m0 = by * 128;
  gemm_core(Ahi, Alo, HH, Bhi, Blo, HH, HH, m0, n0, tid, As, Bs, acc);
#pragma unroll
  for (int mi = 0; mi < 4; ++mi)
#pragma unroll
    for (int r = 0; r < 4; ++r) {
      int m = m0 + wr * 64 + mi * 16 + kg * 4 + r;
      float* dst = L + (size_t)m * NN + n0 + wc * 64 + fr;
#pragma unroll
      for (int ni = 0; ni < 4; ++ni) dst[ni * 16] = acc[mi][ni][r];
    }
}

// ---------------- dB1 = (E @ qn)*sA[m] - sB[m]*B  [MM x HH], K=NN ----------------
__global__ __launch_bounds__(256) void gemm_dB1_k(const u16* __restrict__ Ahi, const u16* __restrict__ Alo,
                                                  const u16* __restrict__ Bhi, const u16* __restrict__ Blo,
                                                  const float* __restrict__ Bm,
                                                  const float* __restrict__ sA,
                                                  const float* __restrict__ sB,
                                                  float* __restrict__ dB1) {
  GEMM_PROLOGUE();
  int bx, by; xcd_swz(bx, by);
  int n0 = bx * 128, m0 = by * 128;
  gemm_core(Ahi, Alo, NN, Bhi, Blo, NN, NN, m0, n0, tid, As, Bs, acc);
#pragma unroll
  for (int mi = 0; mi < 4; ++mi)
#pragma unroll
    for (int r = 0; r < 4; ++r) {
      int m = m0 + wr * 64 + mi * 16 + kg * 4 + r;
      float a = sA[m], bc = sB[m];
      size_t base = (size_t)m * HH + n0 + wc * 64 + fr;
#pragma unroll
      for (int ni = 0; ni < 4; ++ni)
        dB1[base + ni * 16] = acc[mi][ni][r] * a - bc * Bm[base + ni * 16];
    }
}

// ---------------- Gp[slice] = B[slice]^T @ dB1[slice]  [HH x HH], split-K over MM ----------------
__global__ __launch_bounds__(256) void gemm_G_k(const u16* __restrict__ Ahi, const u16* __restrict__ Alo,
                                                const u16* __restrict__ Bhi, const u16* __restrict__ Blo,
                                                float* __restrict__ Gp) {
  GEMM_PROLOGUE();
  int bx, by; xcd_swz(bx, by);
  int n0 = bx * 128, m0 = by * 128;
  int kbase = blockIdx.z * (MM / 8);
  gemm_core(Ahi + kbase, Alo + kbase, MM, Bhi + kbase, Blo + kbase, MM, MM / 8, m0, n0, tid, As, Bs, acc);
  float* dst0 = Gp + (size_t)blockIdx.z * HH * HH;
#pragma unroll
  for (int mi = 0; mi < 4; ++mi)
#pragma unroll
    for (int r = 0; r < 4; ++r) {
      int h1 = m0 + wr * 64 + mi * 16 + kg * 4 + r;
      float* dst = dst0 + (size_t)h1 * HH + n0 + wc * 64 + fr;
#pragma unroll
      for (int ni = 0; ni < 4; ++ni) dst[ni * 16] = acc[mi][ni][r];
    }
}

// ---------------- G = (sum_s Gp[s]) / M ----------------
__global__ __launch_bounds__(256) void reduceG_k(const float* __restrict__ Gp,
                                                 float* __restrict__ G) {
  size_t i = ((size_t)blockIdx.x * 256 + threadIdx.x) * 4;
  f4 s = make_float4(0.f, 0.f, 0.f, 0.f);
#pragma unroll
  for (int sl = 0; sl < 8; ++sl) {
    f4 v = *(const f4*)(Gp + (size_t)sl * HH * HH + i);
    s.x += v.x; s.y += v.y; s.z += v.z; s.w += v.w;
  }
  const float invM = 1.0f / (float)MM;
  s.x *= invM; s.y *= invM; s.z *= invM; s.w *= invM;
  *(f4*)(G + i) = s;
}

// ---------------- upd = (1+c1)*B + c1*(B@G) + c1*dB1 + c2*noise  [MM x HH], K=HH ----------------
__global__ __launch_bounds__(256) void gemm_upd_k(const u16* __restrict__ Ahi, const u16* __restrict__ Alo,
                                                  const u16* __restrict__ Bhi, const u16* __restrict__ Blo,
                                                  const float* __restrict__ Bm,
                                                  const float* __restrict__ noise,
                                                  float* __restrict__ dB1, float c1, float c2) {
  GEMM_PROLOGUE();
  int bx, by; xcd_swz(bx, by);
  int n0 = bx * 128, m0 = by * 128;
  gemm_core(Ahi, Alo, HH, Bhi, Blo, HH, HH, m0, n0, tid, As, Bs, acc);
  const float c1p = 1.0f + c1;
#pragma unroll
  for (int mi = 0; mi < 4; ++mi)
#pragma unroll
    for (int r = 0; r < 4; ++r) {
      int m = m0 + wr * 64 + mi * 16 + kg * 4 + r;
      size_t base = (size_t)m * HH + n0 + wc * 64 + fr;
#pragma unroll
      for (int ni = 0; ni < 4; ++ni) {
        size_t o = base + ni * 16;
        dB1[o] = c1 * acc[mi][ni][r] + c1p * Bm[o] + c1 * dB1[o] + c2 * noise[o];
      }
    }
}

// ---------------- out[n][1+m] = (qn @ B^T)/TEMP  [NN x MM], K=HH; row stride MM+1 ----------------
__global__ __launch_bounds__(256) void gemm_out_k(const u16* __restrict__ Ahi, const u16* __restrict__ Alo,
                                                  const u16* __restrict__ Bhi, const u16* __restrict__ Blo,
                                                  float* __restrict__ out) {
  GEMM_PROLOGUE();
  int bx, by; xcd_swz(bx, by);
  int n0 = bx * 128, m0 = by * 128;  // n0: m-cols, m0: n-rows
  gemm_core(Ahi, Alo, HH, Bhi, Blo, HH, HH, m0, n0, tid, As, Bs, acc);
#pragma unroll
  for (int mi = 0; mi < 4; ++mi)
#pragma unroll
    for (int r = 0; r < 4; ++r) {
      int n = m0 + wr * 64 + mi * 16 + kg * 4 + r;
      float* dst = out + (size_t)n * (MM + 1) + 1 + n0 + wc * 64 + fr;
#pragma unroll
      for (int ni = 0; ni < 4; ++ni) dst[ni * 16] = acc[mi][ni][r] * TEMP_INV;
    }
}

extern "C" void kernel_launch(void* const* d_in, const int* in_sizes, int n_in, void* d_out,
                              int out_size, void* d_ws, size_t ws_size, hipStream_t stream) {
  (void)in_sizes; (void)n_in; (void)out_size; (void)ws_size;
  const float* q = (const float*)d_in[0];
  const float* k = (const float*)d_in[1];
  const float* noise = (const float*)d_in[3];
  float* out = (float*)d_out;

  // ---- workspace carve (bytes, 256B-aligned) ----
  char* w = (char*)d_ws;
  size_t off = 0;
  auto alloc = [&](size_t bytes) -> void* {
    void* p = w + off;
    off = (off + bytes + 255) & ~(size_t)255;
    return p;
  };
  float* qn     = (float*)alloc((size_t)NN * HH * 4);
  u16*   qn_hi  = (u16*)  alloc((size_t)NN * HH * 2);
  u16*   qn_lo  = (u16*)  alloc((size_t)NN * HH * 2);
  u16*   qnT_hi = (u16*)  alloc((size_t)HH * NN * 2);
  u16*   qnT_lo = (u16*)  alloc((size_t)HH * NN * 2);
  float* Bm     = (float*)alloc((size_t)MM * HH * 4);
  u16*   Bm_hi  = (u16*)  alloc((size_t)MM * HH * 2);
  u16*   Bm_lo  = (u16*)  alloc((size_t)MM * HH * 2);
  u16*   BmT_hi = (u16*)  alloc((size_t)HH * MM * 2);
  u16*   BmT_lo = (u16*)  alloc((size_t)HH * MM * 2);
  float* dB1    = (float*)alloc((size_t)MM * HH * 4);
  // E region (dead after gemm_dB1 each iter) overlays Gp and dB1T:
  u16*   E_hi   = (u16*)  alloc((size_t)MM * NN * 2);  // 33.5MB; also Gp (fp32, 8*HH*HH*4 = 32MB)
  u16*   E_lo   = (u16*)  alloc((size_t)MM * NN * 2);  // 33.5MB; also dB1T hi+lo (2 x 16.8MB)
  float* Gp     = (float*)E_hi;
  u16*   dB1T_hi = (u16*)E_lo;
  u16*   dB1T_lo = dB1T_hi + (size_t)HH * MM;
  float* G      = (float*)alloc((size_t)HH * HH * 4);
  u16*   GT_hi  = (u16*)  alloc((size_t)HH * HH * 2);
  u16*   GT_lo  = (u16*)  alloc((size_t)HH * HH * 2);
  float* sA     = (float*)alloc(MM * 4);
  float* sB     = (float*)alloc(MM * 4);
  float* qcm    = (float*)alloc(HH * 4);
  float* L = out;  // [MM][NN] logits scratch inside d_out; fully overwritten at the end

  // ---- setup ----
  rownorm_split_k<<<NN, 256, 0, stream>>>(q, qn, qn_hi, qn_lo);
  transpose_split_k<<<dim3(HH / 32, NN / 32), 256, 0, stream>>>(qn, qnT_hi, qnT_lo, NN, HH);
  colmean_k<<<HH / 256, 256, 0, stream>>>(qn, qcm);
  // iteration 0 exact shortcut (B_init = 0 -> uniform softmax, delta_B = 0)
  init0_k<<<MM, 256, 0, stream>>>(qcm, noise, Bm, Bm_hi, Bm_lo);
  transpose_split_k<<<dim3(HH / 32, MM / 32), 256, 0, stream>>>(Bm, BmT_hi, BmT_lo, MM, HH);

  for (int it = 1; it < ETA_IT; ++it) {
    float t = (float)it + 1.0f;
    float c1 = 0.5f / t;
    float c2 = sqrtf(2.0f / t);
    gemm_L_k<<<dim3(NN / 128, MM / 128), 256, 0, stream>>>(Bm_hi, Bm_lo, qn_hi, qn_lo, L);
    rowstats_k<<<MM, 256, 0, stream>>>(L, E_hi, E_lo, sA, sB);
    gemm_dB1_k<<<dim3(HH / 128, MM / 128), 256, 0, stream>>>(E_hi, E_lo, qnT_hi, qnT_lo, Bm, sA, sB, dB1);
    transpose_split_k<<<dim3(HH / 32, MM / 32), 256, 0, stream>>>(dB1, dB1T_hi, dB1T_lo, MM, HH);
    gemm_G_k<<<dim3(HH / 128, HH / 128, 8), 256, 0, stream>>>(BmT_hi, BmT_lo, dB1T_hi, dB1T_lo, Gp);
    reduceG_k<<<(HH * HH / 4) / 256, 256, 0, stream>>>(Gp, G);
    transpose_split_k<<<dim3(HH / 32, HH / 32), 256, 0, stream>>>(G, GT_hi, GT_lo, HH, HH);
    gemm_upd_k<<<dim3(HH / 128, MM / 128), 256, 0, stream>>>(
        Bm_hi, Bm_lo, GT_hi, GT_lo, Bm, noise + (size_t)it * MM * HH, dB1, c1, c2);
    rownorm_split_k<<<MM, 256, 0, stream>>>(dB1, Bm, Bm_hi, Bm_lo);
    transpose_split_k<<<dim3(HH / 32, MM / 32), 256, 0, stream>>>(Bm, BmT_hi, BmT_lo, MM, HH);
  }

  // ---- final output ----
  cos_k<<<NN, 256, 0, stream>>>(qn, k, out);
  gemm_out_k<<<dim3(MM / 128, NN / 128), 256, 0, stream>>>(qn_hi, qn_lo, Bm_hi, Bm_lo, out);
}